// Round 19
// baseline (775.147 us; speedup 1.0000x reference)
//
#include <hip/hip_runtime.h>

#define NN 4096
#define EE 131072
#define FFD 2048

typedef float f32x4 __attribute__((ext_vector_type(4)));
typedef __bf16 bf16x8 __attribute__((ext_vector_type(8)));
typedef unsigned int u32;
typedef u32 u32x4 __attribute__((ext_vector_type(4)));
typedef unsigned short u16;
typedef u16 u16x8 __attribute__((ext_vector_type(8)));

__device__ __forceinline__ u16 f2bf(float f) {       // explicit RNE
    unsigned u = __builtin_bit_cast(unsigned, f);
    return (u16)((u + 0x7FFFu + ((u >> 16) & 1u)) >> 16);
}
__device__ __forceinline__ float bf2f(u16 h) {
    unsigned u = ((unsigned)h) << 16;
    return __builtin_bit_cast(float, u);
}
__device__ __forceinline__ u32 cvtpk(float lo, float hi) {   // HW pack (validated R17)
    u32 r;
    asm("v_cvt_pk_bf16_f32 %0, %1, %2" : "=v"(r) : "v"(lo), "v"(hi));
    return r;
}

#define GLD16(g, l) __builtin_amdgcn_global_load_lds(                            \
    (const __attribute__((address_space(1))) void*)(g),                          \
    (__attribute__((address_space(3))) void*)(l), 16, 0, 0)

__device__ __forceinline__ int ldedge(const int* ei, int idx, int is64) {
    return is64 ? ei[2 * idx] : ei[idx];
}

// ---------------- init: edge dtype detect (block 0) + cnt zero (blocks 1-16) ----------------
__global__ void k_init(const int* __restrict__ ei, int* __restrict__ flag,
                       int* __restrict__ cnt) {
    if (blockIdx.x == 0) {
        if (threadIdx.x < 64) {
            int v = ei[2 * threadIdx.x + 1];
            unsigned long long any = __ballot(v != 0);
            if (threadIdx.x == 0) *flag = (any == 0ULL) ? 1 : 0;   // 1 => int64
        }
    } else {
        cnt[(blockIdx.x - 1) * 256 + threadIdx.x] = 0;
    }
}

__global__ void k_degi(const int* __restrict__ ei, const int* __restrict__ flag,
                       int* __restrict__ cnt) {
    int e = blockIdx.x * 256 + threadIdx.x;
    if (e >= EE) return;
    atomicAdd(&cnt[ldedge(ei, EE + e, *flag)], 1);
}
// exclusive prefix over cnt[4096] -> rp[4097] + cursor copy + dinv (fused)
__global__ __launch_bounds__(1024) void k_scan(const int* __restrict__ cnt,
        int* __restrict__ rp, int* __restrict__ cur, float* __restrict__ dinv) {
    __shared__ int tsum[1024];
    int t = threadIdx.x;
    int c0 = cnt[t * 4], c1 = cnt[t * 4 + 1], c2 = cnt[t * 4 + 2], c3 = cnt[t * 4 + 3];
    int s = c0 + c1 + c2 + c3;
    tsum[t] = s;
    dinv[t * 4]     = rsqrtf((float)c0 + 1.0f);
    dinv[t * 4 + 1] = rsqrtf((float)c1 + 1.0f);
    dinv[t * 4 + 2] = rsqrtf((float)c2 + 1.0f);
    dinv[t * 4 + 3] = rsqrtf((float)c3 + 1.0f);
    __syncthreads();
    for (int off = 1; off < 1024; off <<= 1) {
        int v = (t >= off) ? tsum[t - off] : 0;
        __syncthreads();
        tsum[t] += v;
        __syncthreads();
    }
    int excl = tsum[t] - s;
    int p0 = excl, p1 = excl + c0, p2 = p1 + c1, p3 = p2 + c2;
    rp[t * 4] = p0; rp[t * 4 + 1] = p1; rp[t * 4 + 2] = p2; rp[t * 4 + 3] = p3;
    cur[t * 4] = p0; cur[t * 4 + 1] = p1; cur[t * 4 + 2] = p2; cur[t * 4 + 3] = p3;
    if (t == 1023) rp[4096] = excl + s;
}

// ---------------- fused: bucket(512) + mm1(2048) + W1T(64) + W2T(64) + prep(1) ----------------
__global__ __launch_bounds__(256) void k_fuse1(const int* __restrict__ ei,
        const int* __restrict__ flag, int* __restrict__ cur, int* __restrict__ es,
        const float* __restrict__ x, const float* __restrict__ Wg1,
        const float* __restrict__ dinv, float* __restrict__ ms,
        const float* __restrict__ W1, const float* __restrict__ W2,
        u16* __restrict__ w1t, u16* __restrict__ w2t,
        const float* __restrict__ Wq, const float* __restrict__ bq,
        const float* __restrict__ Wk, const float* __restrict__ bk,
        const float* __restrict__ Wv, const float* __restrict__ bv,
        const float* __restrict__ Wo, const float* __restrict__ bo,
        float* __restrict__ tc) {
    __shared__ float smem[64 * 65];      // transpose tile; low 384 reused by mm1/prep
    int b = blockIdx.x, t = threadIdx.x;
    if (b < 512) {                       // bucket
        int e = b * 256 + t;
        int is64 = *flag;
        int s = ldedge(ei, e, is64), d = ldedge(ei, EE + e, is64);
        int pos = atomicAdd(&cur[d], 1);
        es[pos] = s;
    } else if (b < 2560) {               // GCN layer-1 mm (2 nodes/block)
        int n0 = (b - 512) * 2, r = t >> 7, e = t & 127;
        smem[r * 128 + e] = x[(size_t)(n0 + r) * 128 + e];
        __syncthreads();
        float a = 0.f;
        #pragma unroll 8
        for (int c = 0; c < 128; ++c) a += smem[r * 128 + c] * Wg1[c * 128 + e];
        ms[(size_t)(n0 + r) * 128 + e] = a * dinv[n0 + r];
    } else if (b < 2624) {               // W1 [128][2048] -> w1t [2048][128], tiled
        int bb = b - 2560;
        int c0 = (bb >> 5) * 64, f0 = (bb & 31) * 64;
        int rr = t >> 6, col = t & 63;
        #pragma unroll
        for (int k = 0; k < 16; ++k) {
            int row = k * 4 + rr;
            smem[row * 65 + col] = W1[(size_t)(c0 + row) * 2048 + f0 + col];
        }
        __syncthreads();
        #pragma unroll
        for (int k = 0; k < 16; ++k) {
            int frow = k * 4 + rr;
            w1t[(size_t)(f0 + frow) * 128 + c0 + col] = f2bf(smem[col * 65 + frow]);
        }
    } else if (b < 2688) {               // W2 [2048][128] -> w2t [128][2048], tiled
        int bb = b - 2624;
        int f0 = (bb >> 1) * 64, o0 = (bb & 1) * 64;
        int rr = t >> 6, col = t & 63;
        #pragma unroll
        for (int k = 0; k < 16; ++k) {
            int row = k * 4 + rr;
            smem[row * 65 + col] = W2[(size_t)(f0 + row) * 128 + o0 + col];
        }
        __syncthreads();
        #pragma unroll
        for (int k = 0; k < 16; ++k) {
            int orow = k * 4 + rr;
            w2t[(size_t)(o0 + orow) * 2048 + f0 + col] = f2bf(smem[col * 65 + orow]);
        }
    } else {                             // prep (tc)
        float aq = 0, ak = 0, av = 0;
        if (t < 128) {
            for (int c = 0; c < 128; ++c) {
                aq += Wq[c * 128 + t]; ak += Wk[c * 128 + t]; av += Wv[c * 128 + t];
            }
            smem[t] = aq; smem[128 + t] = ak; smem[256 + t] = av;
            tc[t] = aq; tc[128 + t] = ak; tc[256 + t] = av;
        }
        __syncthreads();
        if (t < 128) {
            float pb = 0;
            for (int d = 0; d < 128; ++d) pb += bv[d] * Wo[d * 128 + t];
            tc[1440 + t] = pb + bo[t];
            for (int hh = 0; hh < 8; ++hh) {
                float p = 0;
                #pragma unroll
                for (int d = hh * 16; d < hh * 16 + 16; ++d) p += smem[256 + d] * Wo[d * 128 + t];
                tc[416 + hh * 128 + t] = p;
            }
        }
        if (t < 8) {
            float A = 0, B = 0, C = 0, D = 0;
            #pragma unroll
            for (int d = t * 16; d < t * 16 + 16; ++d) {
                A += smem[d] * smem[128 + d]; B += smem[d] * bk[d];
                C += bq[d] * smem[128 + d];   D += bq[d] * bk[d];
            }
            tc[384 + t] = A; tc[392 + t] = B; tc[400 + t] = C; tc[408 + t] = D;
        }
    }
}

// ---------------- fused gather(L, 128-wide) + mm Wg2 -> msB  (4 nodes/block) ----------------
// Gather: one wave per node, identical fp32 op order to k_gath128. Matvec: same
// thread mapping / c-ascending chain as old k_gcn_mm128 (2 passes of 2 nodes).
__global__ __launch_bounds__(256) void k_gm2(const int* __restrict__ es,
        const int* __restrict__ rp, const float* __restrict__ msA,
        const float* __restrict__ dinv, const float* __restrict__ bg,
        const float* __restrict__ W, float* __restrict__ msB) {
    __shared__ float sh[4][128];
    int t = threadIdx.x, n0 = blockIdx.x * 4;
    int wv = t >> 6, lane = t & 63;
    int node = n0 + wv;
    const float2* m2 = (const float2*)msA;
    int st = rp[node], en = rp[node + 1];
    float ax0 = 0.f, ay0 = 0.f, ax1 = 0.f, ay1 = 0.f;
    int e = st;
    for (; e + 2 <= en; e += 2) {
        int s0 = es[e], s1 = es[e + 1];
        float2 v0 = m2[(size_t)s0 * 64 + lane];
        float2 v1 = m2[(size_t)s1 * 64 + lane];
        ax0 += v0.x; ay0 += v0.y; ax1 += v1.x; ay1 += v1.y;
    }
    if (e < en) {
        float2 v = m2[(size_t)es[e] * 64 + lane];
        ax0 += v.x; ay0 += v.y;
    }
    float dv = dinv[node];
    float2 self = m2[(size_t)node * 64 + lane];
    int c = lane * 2;
    sh[wv][c]     = fmaxf(dv * (ax0 + ax1 + self.x) + bg[c], 0.f);
    sh[wv][c + 1] = fmaxf(dv * (ay0 + ay1 + self.y) + bg[c + 1], 0.f);
    __syncthreads();
    int e2 = t & 127;
    #pragma unroll
    for (int p = 0; p < 2; ++p) {
        int ni = p * 2 + (t >> 7);
        float a = 0.f;
        #pragma unroll 8
        for (int cc = 0; cc < 128; ++cc) a += sh[ni][cc] * W[cc * 128 + e2];
        msB[(size_t)(n0 + ni) * 128 + e2] = a * dinv[n0 + ni];
    }
}

// ---------------- fused gather(L, 128-wide) + mm Wg3 (32-wide) -> ms32 ----------------
__global__ __launch_bounds__(256) void k_gm3(const int* __restrict__ es,
        const int* __restrict__ rp, const float* __restrict__ msB,
        const float* __restrict__ dinv, const float* __restrict__ bg,
        const float* __restrict__ W, float* __restrict__ ms32) {
    __shared__ float sh[4][128];
    int t = threadIdx.x, n0 = blockIdx.x * 4;
    int wv = t >> 6, lane = t & 63;
    int node = n0 + wv;
    const float2* m2 = (const float2*)msB;
    int st = rp[node], en = rp[node + 1];
    float ax0 = 0.f, ay0 = 0.f, ax1 = 0.f, ay1 = 0.f;
    int e = st;
    for (; e + 2 <= en; e += 2) {
        int s0 = es[e], s1 = es[e + 1];
        float2 v0 = m2[(size_t)s0 * 64 + lane];
        float2 v1 = m2[(size_t)s1 * 64 + lane];
        ax0 += v0.x; ay0 += v0.y; ax1 += v1.x; ay1 += v1.y;
    }
    if (e < en) {
        float2 v = m2[(size_t)es[e] * 64 + lane];
        ax0 += v.x; ay0 += v.y;
    }
    float dv = dinv[node];
    float2 self = m2[(size_t)node * 64 + lane];
    int c = lane * 2;
    sh[wv][c]     = fmaxf(dv * (ax0 + ax1 + self.x) + bg[c], 0.f);
    sh[wv][c + 1] = fmaxf(dv * (ay0 + ay1 + self.y) + bg[c + 1], 0.f);
    __syncthreads();
    if (t < 128) {
        int ni = t >> 5, e2 = t & 31;
        float a = 0.f;
        #pragma unroll 8
        for (int cc = 0; cc < 128; ++cc) a += sh[ni][cc] * W[cc * 32 + e2];
        ms32[(size_t)(n0 + ni) * 32 + e2] = a * dinv[n0 + ni];
    }
}

// ---------------- fused gather(dout=32) + attention + LN1 -> x1 (bf16) ----------------
__global__ __launch_bounds__(256) void k_ga(const int* __restrict__ es,
        const int* __restrict__ rp, const float* __restrict__ ms,
        const float* __restrict__ dinv, const float* __restrict__ bg3,
        const float* __restrict__ tc, const float* __restrict__ g1,
        const float* __restrict__ b1n, u16* __restrict__ x1b) {
    __shared__ float sh[2][32];
    __shared__ float wsm[2][8][32];
    int b = blockIdx.x, t = threadIdx.x;
    int n0 = b * 2;
    if (t < 64) {
        int ni = t >> 5, sl = t & 31;
        int node = n0 + ni;
        int st = rp[node], en = rp[node + 1];
        float a0 = 0.f, a1 = 0.f;
        int e = st;
        for (; e + 2 <= en; e += 2) {
            a0 += ms[(size_t)es[e] * 32 + sl];
            a1 += ms[(size_t)es[e + 1] * 32 + sl];
        }
        if (e < en) a0 += ms[(size_t)es[e] * 32 + sl];
        float dv = dinv[node];
        sh[ni][sl] = fmaxf(dv * (a0 + a1 + ms[(size_t)node * 32 + sl]) + bg3[sl], 0.f);
    }
    __syncthreads();
    #pragma unroll
    for (int rep = 0; rep < 2; ++rep) {
        int idx = rep * 256 + t;
        int ni = idx >> 8, hh = (idx >> 5) & 7, i = idx & 31;
        float A = tc[384 + hh], C = tc[400 + hh];
        float coef = (sh[ni][i] * A + C) * 0.25f;
        float m = -1e30f;
        #pragma unroll
        for (int j = 0; j < 32; ++j) m = fmaxf(m, coef * sh[ni][j]);
        float s = 0.f, wsum = 0.f;
        #pragma unroll
        for (int j = 0; j < 32; ++j) {
            float e = __expf(coef * sh[ni][j] - m);
            s += e; wsum += e * sh[ni][j];
        }
        wsm[ni][hh][i] = wsum / s;
    }
    __syncthreads();
    int wave = t >> 6, lane = t & 63;
    int ni = wave >> 1;
    float pb0 = tc[1440 + lane], pb1 = tc[1440 + lane + 64];
    float po0[8], po1[8];
    #pragma unroll
    for (int hh = 0; hh < 8; ++hh) {
        po0[hh] = tc[416 + hh * 128 + lane];
        po1[hh] = tc[416 + hh * 128 + lane + 64];
    }
    float ga = g1[lane], gb = g1[lane + 64], ba = b1n[lane], bb = b1n[lane + 64];
    size_t nbase = (size_t)(n0 + ni) * 32;
    for (int i = (wave & 1); i < 32; i += 2) {
        float y0 = sh[ni][i] + pb0, y1 = sh[ni][i] + pb1;
        #pragma unroll
        for (int hh = 0; hh < 8; ++hh) {
            float w = wsm[ni][hh][i];
            y0 += w * po0[hh]; y1 += w * po1[hh];
        }
        float s1 = y0 + y1, s2 = y0 * y0 + y1 * y1;
        #pragma unroll
        for (int off = 1; off < 64; off <<= 1) {
            s1 += __shfl_xor(s1, off); s2 += __shfl_xor(s2, off);
        }
        float mu = s1 * (1.f / 128.f);
        float var = s2 * (1.f / 128.f) - mu * mu;
        float rs = rsqrtf(var + 1e-5f);
        size_t base = (nbase + i) * 128;
        x1b[base + lane]      = f2bf((y0 - mu) * rs * ga + ba);
        x1b[base + lane + 64] = f2bf((y1 - mu) * rs * gb + bb);
    }
}

// ---------------- fused FFN + residual + LN2 (R17 structure, 4 blocks/CU) ----------------
#define STAGE32(buf, Fb) {                                                       \
    char* db_ = (char*)(buf);                                                    \
    _Pragma("unroll") for (int c1_ = 0; c1_ < 2; ++c1_) {                        \
        int f_ = c1_ * 16 + (t >> 4);                                            \
        int bo_ = ((t & 15) * 16) ^ ((f_ & 7) << 4);                             \
        GLD16(w1t + (size_t)((Fb) + f_) * 128 + (bo_ >> 1),                      \
              db_ + c1_ * 4096 + wave * 1024);                                   \
    }                                                                            \
    _Pragma("unroll") for (int c2_ = 0; c2_ < 2; ++c2_) {                        \
        int op_ = c2_ * 32 + wave * 8 + ((t >> 3) & 7);                          \
        int pb_ = (t & 7) ^ ((t >> 3) & 7);                                      \
        int o_  = op_ * 2 + (pb_ >> 2);                                          \
        GLD16(w2t + (size_t)o_ * 2048 + (Fb) + (pb_ & 3) * 8,                    \
              db_ + 8192 + c2_ * 4096 + wave * 1024);                            \
    } }

#define FCOMP32(buf, Fb) {                                                       \
    const char* wb_ = (const char*)(buf);                                        \
    bf16x8 w2f_[8];                                                              \
    _Pragma("unroll") for (int c2_ = 0; c2_ < 8; ++c2_)                          \
        w2f_[c2_] = *(const bf16x8*)(wb_ + 8192 + (c2_ * 8 + (li >> 1)) * 128 +  \
            ((((li & 1) * 64) + g * 16) ^ ((li >> 1) << 4)));                    \
    _Pragma("unroll") for (int cf_ = 0; cf_ < 2; ++cf_) {                        \
        bf16x8 w1f_[4];                                                          \
        _Pragma("unroll") for (int ks_ = 0; ks_ < 4; ++ks_)                      \
            w1f_[ks_] = *(const bf16x8*)(wb_ + (cf_ * 16 + li) * 256 +           \
                ((ks_ * 64 + g * 16) ^ ((li & 7) << 4)));                        \
        f32x4 a0_ = (f32x4){0.f, 0.f, 0.f, 0.f};                                 \
        f32x4 a1_ = (f32x4){0.f, 0.f, 0.f, 0.f};                                 \
        _Pragma("unroll") for (int ks_ = 0; ks_ < 4; ++ks_) {                    \
            a0_ = __builtin_amdgcn_mfma_f32_16x16x32_bf16(af[0][ks_], w1f_[ks_], a0_, 0, 0, 0); \
            a1_ = __builtin_amdgcn_mfma_f32_16x16x32_bf16(af[1][ks_], w1f_[ks_], a1_, 0, 0, 0); \
        }                                                                        \
        float bias_ = b1[(Fb) + cf_ * 16 + li];                                  \
        u32 pkA0 = cvtpk(fmaxf(a0_[0] + bias_, 0.f), fmaxf(a0_[1] + bias_, 0.f)); \
        u32 pkA1 = cvtpk(fmaxf(a0_[2] + bias_, 0.f), fmaxf(a0_[3] + bias_, 0.f)); \
        u32 pkB0 = cvtpk(fmaxf(a1_[0] + bias_, 0.f), fmaxf(a1_[1] + bias_, 0.f)); \
        u32 pkB1 = cvtpk(fmaxf(a1_[2] + bias_, 0.f), fmaxf(a1_[3] + bias_, 0.f)); \
        int rp0_ = g * 2, rp1_ = g * 2 + 1;                                      \
        int wl_ = (cf_ * 16 + li) * 2;                                           \
        *(u16*)(hwb + rp0_ * 128 + ((wl_) ^ (rp0_ << 4)))        = (u16)pkA0;    \
        *(u16*)(hwb + rp0_ * 128 + ((64 + wl_) ^ (rp0_ << 4)))   = (u16)(pkA0 >> 16); \
        *(u16*)(hwb + rp1_ * 128 + ((wl_) ^ (rp1_ << 4)))        = (u16)pkA1;    \
        *(u16*)(hwb + rp1_ * 128 + ((64 + wl_) ^ (rp1_ << 4)))   = (u16)(pkA1 >> 16); \
        *(u16*)(hwb + (8 + rp0_) * 128 + ((wl_) ^ (rp0_ << 4)))      = (u16)pkB0; \
        *(u16*)(hwb + (8 + rp0_) * 128 + ((64 + wl_) ^ (rp0_ << 4))) = (u16)(pkB0 >> 16); \
        *(u16*)(hwb + (8 + rp1_) * 128 + ((wl_) ^ (rp1_ << 4)))      = (u16)pkB1; \
        *(u16*)(hwb + (8 + rp1_) * 128 + ((64 + wl_) ^ (rp1_ << 4))) = (u16)(pkB1 >> 16); \
    }                                                                            \
    {                                                                            \
        bf16x8 a2_[2];                                                           \
        _Pragma("unroll") for (int rf_ = 0; rf_ < 2; ++rf_)                      \
            a2_[rf_] = *(const bf16x8*)(hwb + (rf_ * 8 + (li >> 1)) * 128 +      \
                ((((li & 1) * 64) + g * 16) ^ ((li >> 1) << 4)));                \
        _Pragma("unroll") for (int c2_ = 0; c2_ < 8; ++c2_) {                    \
            acc2[0][c2_] = __builtin_amdgcn_mfma_f32_16x16x32_bf16(a2_[0], w2f_[c2_], acc2[0][c2_], 0, 0, 0); \
            acc2[1][c2_] = __builtin_amdgcn_mfma_f32_16x16x32_bf16(a2_[1], w2f_[c2_], acc2[1][c2_], 0, 0, 0); \
        }                                                                        \
    } }

__global__ __launch_bounds__(256, 4) void k_ffn(const u16* __restrict__ x1b,
        const u16* __restrict__ w1t, const u16* __restrict__ w2t,
        const float* __restrict__ b1, const float* __restrict__ b2,
        const float* __restrict__ g2, const float* __restrict__ bt2, float* __restrict__ out) {
    __shared__ u16 wA[8192];            // 16KB: W1 chunk (8KB) + W2 chunk (8KB)
    __shared__ u16 wB[8192];            // 16KB: buffer B
    __shared__ u16 hid[4][1024];        // per-wave [16 rp][128B] bf16 hidden (8KB total)
    int t = threadIdx.x, wave = t >> 6, lane = t & 63;
    int g = lane >> 4, li = lane & 15;
    size_t rowbase = (size_t)blockIdx.x * 128;
    char* hwb = (char*)&hid[wave][0];

    STAGE32(wA, 0);

    bf16x8 af[2][4];
    #pragma unroll
    for (int rf = 0; rf < 2; ++rf)
    #pragma unroll
    for (int ks = 0; ks < 4; ++ks)
        af[rf][ks] = *(const bf16x8*)(x1b +
            (rowbase + wave * 32 + rf * 16 + li) * 128 + ks * 32 + g * 8);

    f32x4 acc2[2][8];
    #pragma unroll
    for (int a = 0; a < 2; ++a)
    #pragma unroll
    for (int b = 0; b < 8; ++b) acc2[a][b] = (f32x4){0.f, 0.f, 0.f, 0.f};

    __syncthreads();                    // wA staged

    for (int F = 0; F < FFD; F += 64) {
        STAGE32(wB, F + 32);
        FCOMP32(wA, F);
        __syncthreads();
        if (F + 64 < FFD) STAGE32(wA, F + 64);
        FCOMP32(wB, F + 32);
        __syncthreads();
    }

    #pragma unroll
    for (int rf = 0; rf < 2; ++rf)
    #pragma unroll
    for (int r = 0; r < 4; ++r) {
        int lrow = wave * 32 + rf * 16 + g * 4 + r;
        size_t grow = rowbase + lrow;
        float vals[8], s1 = 0.f, s2 = 0.f;
        #pragma unroll
        for (int cf2 = 0; cf2 < 8; ++cf2) {
            int col = cf2 * 16 + li;
            float xv = bf2f(x1b[grow * 128 + col]);
            float y = xv + acc2[rf][cf2][r] + b2[col];
            vals[cf2] = y; s1 += y; s2 += y * y;
        }
        #pragma unroll
        for (int m = 1; m < 16; m <<= 1) {
            s1 += __shfl_xor(s1, m); s2 += __shfl_xor(s2, m);
        }
        float mu = s1 * (1.f / 128.f);
        float var = s2 * (1.f / 128.f) - mu * mu;
        float rs = rsqrtf(var + 1e-5f);
        #pragma unroll
        for (int cf2 = 0; cf2 < 8; ++cf2) {
            int col = cf2 * 16 + li;
            out[grow * 128 + col] = (vals[cf2] - mu) * rs * g2[col] + bt2[col];
        }
    }
}

// ---------------- launch ----------------
extern "C" void kernel_launch(void* const* d_in, const int* in_sizes, int n_in,
                              void* d_out, int out_size, void* d_ws, size_t ws_size,
                              hipStream_t stream) {
    const float* x   = (const float*)d_in[0];
    const int*   ei  = (const int*)d_in[1];
    const float *Wg1 = (const float*)d_in[2],  *bg1 = (const float*)d_in[3];
    const float *Wg2 = (const float*)d_in[4],  *bg2 = (const float*)d_in[5];
    const float *Wg3 = (const float*)d_in[6],  *bg3 = (const float*)d_in[7];
    const float *Wq  = (const float*)d_in[8],  *bq  = (const float*)d_in[9];
    const float *Wk  = (const float*)d_in[10], *bk  = (const float*)d_in[11];
    const float *Wv  = (const float*)d_in[12], *bv  = (const float*)d_in[13];
    const float *Wo  = (const float*)d_in[14], *bo  = (const float*)d_in[15];
    const float *g1  = (const float*)d_in[16], *b1n = (const float*)d_in[17];
    const float *W1  = (const float*)d_in[18], *b1  = (const float*)d_in[19];
    const float *W2  = (const float*)d_in[20], *b2  = (const float*)d_in[21];
    const float *g2  = (const float*)d_in[22], *bt2 = (const float*)d_in[23];

    char* ws = (char*)d_ws;
    int*   flag = (int*)(ws + 0);
    int*   cnt  = (int*)(ws + 4096);
    int*   rp   = (int*)(ws + 20480);
    int*   cur  = (int*)(ws + 40960);
    float* dinv = (float*)(ws + 57344);
    float* msA  = (float*)(ws + 73728);      // 2 MB (L1 ms, later ms32)
    int*   es   = (int*)(ws + 2170880);      // 512 KB
    float* msB  = (float*)(ws + 2695168);    // 2 MB (L2 ms)
    float* tc   = (float*)(ws + 6889472);
    u16*   w1t  = (u16*)(ws + 6897664);      // 512 KB
    u16*   w2t  = (u16*)(ws + 7421952);      // 512 KB
    u16*   x1b  = (u16*)(ws + 8388608);      // 32 MB bf16 x1
    float* ms32 = msA;                       // reuse L1 buffer for 32-wide ms
    float* out  = (float*)d_out;

    k_init<<<17, 256, 0, stream>>>(ei, flag, cnt);
    k_degi<<<512, 256, 0, stream>>>(ei, flag, cnt);
    k_scan<<<1, 1024, 0, stream>>>(cnt, rp, cur, dinv);

    // fused: bucket + GCN mm1 + tiled weight transpose + prep  (mm1 -> msA)
    k_fuse1<<<2689, 256, 0, stream>>>(ei, flag, cur, es, x, Wg1, dinv, msA,
                                      W1, W2, w1t, w2t,
                                      Wq, bq, Wk, bk, Wv, bv, Wo, bo, tc);

    // gather L1 + mm Wg2 -> msB ; gather L2 + mm Wg3 -> ms32
    k_gm2<<<1024, 256, 0, stream>>>(es, rp, msA, dinv, bg1, Wg2, msB);
    k_gm3<<<1024, 256, 0, stream>>>(es, rp, msB, dinv, bg2, Wg3, ms32);

    // fused gather(32) + attention + LN1 -> x1 (bf16)
    k_ga<<<2048, 256, 0, stream>>>(es, rp, ms32, dinv, bg3, tc, g1, b1n, x1b);

    // FFN + residual + LN2 -> out (fp32, d_out)
    k_ffn<<<1024, 256, 0, stream>>>(x1b, w1t, w2t, b1, b2, g2, bt2, out);
}

// Round 20
// 278.857 us; speedup vs baseline: 2.7797x; 2.7797x over previous
//
#include <hip/hip_runtime.h>

#define NN 4096
#define EE 131072
#define FFD 2048

typedef float f32x4 __attribute__((ext_vector_type(4)));
typedef __bf16 bf16x8 __attribute__((ext_vector_type(8)));
typedef unsigned int u32;
typedef u32 u32x4 __attribute__((ext_vector_type(4)));
typedef unsigned short u16;
typedef u16 u16x8 __attribute__((ext_vector_type(8)));

__device__ __forceinline__ u16 f2bf(float f) {       // explicit RNE
    unsigned u = __builtin_bit_cast(unsigned, f);
    return (u16)((u + 0x7FFFu + ((u >> 16) & 1u)) >> 16);
}
__device__ __forceinline__ float bf2f(u16 h) {
    unsigned u = ((unsigned)h) << 16;
    return __builtin_bit_cast(float, u);
}
__device__ __forceinline__ u32 cvtpk(float lo, float hi) {   // HW pack (validated R17)
    u32 r;
    asm("v_cvt_pk_bf16_f32 %0, %1, %2" : "=v"(r) : "v"(lo), "v"(hi));
    return r;
}

#define GLD16(g, l) __builtin_amdgcn_global_load_lds(                            \
    (const __attribute__((address_space(1))) void*)(g),                          \
    (__attribute__((address_space(3))) void*)(l), 16, 0, 0)

__device__ __forceinline__ int ldedge(const int* ei, int idx, int is64) {
    return is64 ? ei[2 * idx] : ei[idx];
}

// ---------------- init: edge dtype detect (block 0) + cnt zero (blocks 1-16) ----------------
__global__ void k_init(const int* __restrict__ ei, int* __restrict__ flag,
                       int* __restrict__ cnt) {
    if (blockIdx.x == 0) {
        if (threadIdx.x < 64) {
            int v = ei[2 * threadIdx.x + 1];
            unsigned long long any = __ballot(v != 0);
            if (threadIdx.x == 0) *flag = (any == 0ULL) ? 1 : 0;   // 1 => int64
        }
    } else {
        cnt[(blockIdx.x - 1) * 256 + threadIdx.x] = 0;
    }
}

__global__ void k_degi(const int* __restrict__ ei, const int* __restrict__ flag,
                       int* __restrict__ cnt) {
    int e = blockIdx.x * 256 + threadIdx.x;
    if (e >= EE) return;
    atomicAdd(&cnt[ldedge(ei, EE + e, *flag)], 1);
}
// exclusive prefix over cnt[4096] -> rp[4097] + cursor copy + dinv (fused)
__global__ __launch_bounds__(1024) void k_scan(const int* __restrict__ cnt,
        int* __restrict__ rp, int* __restrict__ cur, float* __restrict__ dinv) {
    __shared__ int tsum[1024];
    int t = threadIdx.x;
    int c0 = cnt[t * 4], c1 = cnt[t * 4 + 1], c2 = cnt[t * 4 + 2], c3 = cnt[t * 4 + 3];
    int s = c0 + c1 + c2 + c3;
    tsum[t] = s;
    dinv[t * 4]     = rsqrtf((float)c0 + 1.0f);
    dinv[t * 4 + 1] = rsqrtf((float)c1 + 1.0f);
    dinv[t * 4 + 2] = rsqrtf((float)c2 + 1.0f);
    dinv[t * 4 + 3] = rsqrtf((float)c3 + 1.0f);
    __syncthreads();
    for (int off = 1; off < 1024; off <<= 1) {
        int v = (t >= off) ? tsum[t - off] : 0;
        __syncthreads();
        tsum[t] += v;
        __syncthreads();
    }
    int excl = tsum[t] - s;
    int p0 = excl, p1 = excl + c0, p2 = p1 + c1, p3 = p2 + c2;
    rp[t * 4] = p0; rp[t * 4 + 1] = p1; rp[t * 4 + 2] = p2; rp[t * 4 + 3] = p3;
    cur[t * 4] = p0; cur[t * 4 + 1] = p1; cur[t * 4 + 2] = p2; cur[t * 4 + 3] = p3;
    if (t == 1023) rp[4096] = excl + s;
}

// ---------------- fused: bucket(512) + mm1(2048) + W1T(64) + W2T(64) + prep(1) ----------------
__global__ __launch_bounds__(256) void k_fuse1(const int* __restrict__ ei,
        const int* __restrict__ flag, int* __restrict__ cur, int* __restrict__ es,
        const float* __restrict__ x, const float* __restrict__ Wg1,
        const float* __restrict__ dinv, float* __restrict__ ms,
        const float* __restrict__ W1, const float* __restrict__ W2,
        u16* __restrict__ w1t, u16* __restrict__ w2t,
        const float* __restrict__ Wq, const float* __restrict__ bq,
        const float* __restrict__ Wk, const float* __restrict__ bk,
        const float* __restrict__ Wv, const float* __restrict__ bv,
        const float* __restrict__ Wo, const float* __restrict__ bo,
        float* __restrict__ tc) {
    __shared__ float smem[64 * 65];      // transpose tile; low 384 reused by mm1/prep
    int b = blockIdx.x, t = threadIdx.x;
    if (b < 512) {                       // bucket
        int e = b * 256 + t;
        int is64 = *flag;
        int s = ldedge(ei, e, is64), d = ldedge(ei, EE + e, is64);
        int pos = atomicAdd(&cur[d], 1);
        es[pos] = s;
    } else if (b < 2560) {               // GCN layer-1 mm (2 nodes/block)
        int n0 = (b - 512) * 2, r = t >> 7, e = t & 127;
        smem[r * 128 + e] = x[(size_t)(n0 + r) * 128 + e];
        __syncthreads();
        float a = 0.f;
        #pragma unroll 8
        for (int c = 0; c < 128; ++c) a += smem[r * 128 + c] * Wg1[c * 128 + e];
        ms[(size_t)(n0 + r) * 128 + e] = a * dinv[n0 + r];
    } else if (b < 2624) {               // W1 [128][2048] -> w1t [2048][128], tiled
        int bb = b - 2560;
        int c0 = (bb >> 5) * 64, f0 = (bb & 31) * 64;
        int rr = t >> 6, col = t & 63;
        #pragma unroll
        for (int k = 0; k < 16; ++k) {
            int row = k * 4 + rr;
            smem[row * 65 + col] = W1[(size_t)(c0 + row) * 2048 + f0 + col];
        }
        __syncthreads();
        #pragma unroll
        for (int k = 0; k < 16; ++k) {
            int frow = k * 4 + rr;
            w1t[(size_t)(f0 + frow) * 128 + c0 + col] = f2bf(smem[col * 65 + frow]);
        }
    } else if (b < 2688) {               // W2 [2048][128] -> w2t [128][2048], tiled
        int bb = b - 2624;
        int f0 = (bb >> 1) * 64, o0 = (bb & 1) * 64;
        int rr = t >> 6, col = t & 63;
        #pragma unroll
        for (int k = 0; k < 16; ++k) {
            int row = k * 4 + rr;
            smem[row * 65 + col] = W2[(size_t)(f0 + row) * 128 + o0 + col];
        }
        __syncthreads();
        #pragma unroll
        for (int k = 0; k < 16; ++k) {
            int orow = k * 4 + rr;
            w2t[(size_t)(o0 + orow) * 2048 + f0 + col] = f2bf(smem[col * 65 + orow]);
        }
    } else {                             // prep (tc)
        float aq = 0, ak = 0, av = 0;
        if (t < 128) {
            for (int c = 0; c < 128; ++c) {
                aq += Wq[c * 128 + t]; ak += Wk[c * 128 + t]; av += Wv[c * 128 + t];
            }
            smem[t] = aq; smem[128 + t] = ak; smem[256 + t] = av;
            tc[t] = aq; tc[128 + t] = ak; tc[256 + t] = av;
        }
        __syncthreads();
        if (t < 128) {
            float pb = 0;
            for (int d = 0; d < 128; ++d) pb += bv[d] * Wo[d * 128 + t];
            tc[1440 + t] = pb + bo[t];
            for (int hh = 0; hh < 8; ++hh) {
                float p = 0;
                #pragma unroll
                for (int d = hh * 16; d < hh * 16 + 16; ++d) p += smem[256 + d] * Wo[d * 128 + t];
                tc[416 + hh * 128 + t] = p;
            }
        }
        if (t < 8) {
            float A = 0, B = 0, C = 0, D = 0;
            #pragma unroll
            for (int d = t * 16; d < t * 16 + 16; ++d) {
                A += smem[d] * smem[128 + d]; B += smem[d] * bk[d];
                C += bq[d] * smem[128 + d];   D += bq[d] * bk[d];
            }
            tc[384 + t] = A; tc[392 + t] = B; tc[400 + t] = C; tc[408 + t] = D;
        }
    }
}

// ---------------- fused gather(L, 128-wide) + mm Wg2 -> msB  (4 nodes/block) ----------------
__global__ __launch_bounds__(256) void k_gm2(const int* __restrict__ es,
        const int* __restrict__ rp, const float* __restrict__ msA,
        const float* __restrict__ dinv, const float* __restrict__ bg,
        const float* __restrict__ W, float* __restrict__ msB) {
    __shared__ float sh[4][128];
    int t = threadIdx.x, n0 = blockIdx.x * 4;
    int wv = t >> 6, lane = t & 63;
    int node = n0 + wv;
    const float2* m2 = (const float2*)msA;
    int st = rp[node], en = rp[node + 1];
    float ax0 = 0.f, ay0 = 0.f, ax1 = 0.f, ay1 = 0.f;
    int e = st;
    for (; e + 2 <= en; e += 2) {
        int s0 = es[e], s1 = es[e + 1];
        float2 v0 = m2[(size_t)s0 * 64 + lane];
        float2 v1 = m2[(size_t)s1 * 64 + lane];
        ax0 += v0.x; ay0 += v0.y; ax1 += v1.x; ay1 += v1.y;
    }
    if (e < en) {
        float2 v = m2[(size_t)es[e] * 64 + lane];
        ax0 += v.x; ay0 += v.y;
    }
    float dv = dinv[node];
    float2 self = m2[(size_t)node * 64 + lane];
    int c = lane * 2;
    sh[wv][c]     = fmaxf(dv * (ax0 + ax1 + self.x) + bg[c], 0.f);
    sh[wv][c + 1] = fmaxf(dv * (ay0 + ay1 + self.y) + bg[c + 1], 0.f);
    __syncthreads();
    int e2 = t & 127;
    #pragma unroll
    for (int p = 0; p < 2; ++p) {
        int ni = p * 2 + (t >> 7);
        float a = 0.f;
        #pragma unroll 8
        for (int cc = 0; cc < 128; ++cc) a += sh[ni][cc] * W[cc * 128 + e2];
        msB[(size_t)(n0 + ni) * 128 + e2] = a * dinv[n0 + ni];
    }
}

// ---------------- fused gather(L, 128-wide) + mm Wg3 (32-wide) -> ms32 ----------------
__global__ __launch_bounds__(256) void k_gm3(const int* __restrict__ es,
        const int* __restrict__ rp, const float* __restrict__ msB,
        const float* __restrict__ dinv, const float* __restrict__ bg,
        const float* __restrict__ W, float* __restrict__ ms32) {
    __shared__ float sh[4][128];
    int t = threadIdx.x, n0 = blockIdx.x * 4;
    int wv = t >> 6, lane = t & 63;
    int node = n0 + wv;
    const float2* m2 = (const float2*)msB;
    int st = rp[node], en = rp[node + 1];
    float ax0 = 0.f, ay0 = 0.f, ax1 = 0.f, ay1 = 0.f;
    int e = st;
    for (; e + 2 <= en; e += 2) {
        int s0 = es[e], s1 = es[e + 1];
        float2 v0 = m2[(size_t)s0 * 64 + lane];
        float2 v1 = m2[(size_t)s1 * 64 + lane];
        ax0 += v0.x; ay0 += v0.y; ax1 += v1.x; ay1 += v1.y;
    }
    if (e < en) {
        float2 v = m2[(size_t)es[e] * 64 + lane];
        ax0 += v.x; ay0 += v.y;
    }
    float dv = dinv[node];
    float2 self = m2[(size_t)node * 64 + lane];
    int c = lane * 2;
    sh[wv][c]     = fmaxf(dv * (ax0 + ax1 + self.x) + bg[c], 0.f);
    sh[wv][c + 1] = fmaxf(dv * (ay0 + ay1 + self.y) + bg[c + 1], 0.f);
    __syncthreads();
    if (t < 128) {
        int ni = t >> 5, e2 = t & 31;
        float a = 0.f;
        #pragma unroll 8
        for (int cc = 0; cc < 128; ++cc) a += sh[ni][cc] * W[cc * 32 + e2];
        ms32[(size_t)(n0 + ni) * 32 + e2] = a * dinv[n0 + ni];
    }
}

// ---------------- fused gather(dout=32) + attention + LN1 -> x1 (bf16) ----------------
__global__ __launch_bounds__(256) void k_ga(const int* __restrict__ es,
        const int* __restrict__ rp, const float* __restrict__ ms,
        const float* __restrict__ dinv, const float* __restrict__ bg3,
        const float* __restrict__ tc, const float* __restrict__ g1,
        const float* __restrict__ b1n, u16* __restrict__ x1b) {
    __shared__ float sh[2][32];
    __shared__ float wsm[2][8][32];
    int b = blockIdx.x, t = threadIdx.x;
    int n0 = b * 2;
    if (t < 64) {
        int ni = t >> 5, sl = t & 31;
        int node = n0 + ni;
        int st = rp[node], en = rp[node + 1];
        float a0 = 0.f, a1 = 0.f;
        int e = st;
        for (; e + 2 <= en; e += 2) {
            a0 += ms[(size_t)es[e] * 32 + sl];
            a1 += ms[(size_t)es[e + 1] * 32 + sl];
        }
        if (e < en) a0 += ms[(size_t)es[e] * 32 + sl];
        float dv = dinv[node];
        sh[ni][sl] = fmaxf(dv * (a0 + a1 + ms[(size_t)node * 32 + sl]) + bg3[sl], 0.f);
    }
    __syncthreads();
    #pragma unroll
    for (int rep = 0; rep < 2; ++rep) {
        int idx = rep * 256 + t;
        int ni = idx >> 8, hh = (idx >> 5) & 7, i = idx & 31;
        float A = tc[384 + hh], C = tc[400 + hh];
        float coef = (sh[ni][i] * A + C) * 0.25f;
        float m = -1e30f;
        #pragma unroll
        for (int j = 0; j < 32; ++j) m = fmaxf(m, coef * sh[ni][j]);
        float s = 0.f, wsum = 0.f;
        #pragma unroll
        for (int j = 0; j < 32; ++j) {
            float e = __expf(coef * sh[ni][j] - m);
            s += e; wsum += e * sh[ni][j];
        }
        wsm[ni][hh][i] = wsum / s;
    }
    __syncthreads();
    int wave = t >> 6, lane = t & 63;
    int ni = wave >> 1;
    float pb0 = tc[1440 + lane], pb1 = tc[1440 + lane + 64];
    float po0[8], po1[8];
    #pragma unroll
    for (int hh = 0; hh < 8; ++hh) {
        po0[hh] = tc[416 + hh * 128 + lane];
        po1[hh] = tc[416 + hh * 128 + lane + 64];
    }
    float ga = g1[lane], gb = g1[lane + 64], ba = b1n[lane], bb = b1n[lane + 64];
    size_t nbase = (size_t)(n0 + ni) * 32;
    for (int i = (wave & 1); i < 32; i += 2) {
        float y0 = sh[ni][i] + pb0, y1 = sh[ni][i] + pb1;
        #pragma unroll
        for (int hh = 0; hh < 8; ++hh) {
            float w = wsm[ni][hh][i];
            y0 += w * po0[hh]; y1 += w * po1[hh];
        }
        float s1 = y0 + y1, s2 = y0 * y0 + y1 * y1;
        #pragma unroll
        for (int off = 1; off < 64; off <<= 1) {
            s1 += __shfl_xor(s1, off); s2 += __shfl_xor(s2, off);
        }
        float mu = s1 * (1.f / 128.f);
        float var = s2 * (1.f / 128.f) - mu * mu;
        float rs = rsqrtf(var + 1e-5f);
        size_t base = (nbase + i) * 128;
        x1b[base + lane]      = f2bf((y0 - mu) * rs * ga + ba);
        x1b[base + lane + 64] = f2bf((y1 - mu) * rs * gb + bb);
    }
}

// ---------------- fused FFN + residual + LN2 (R17 structure; (256,3) — (256,4) spills!) ----------------
#define STAGE32(buf, Fb) {                                                       \
    char* db_ = (char*)(buf);                                                    \
    _Pragma("unroll") for (int c1_ = 0; c1_ < 2; ++c1_) {                        \
        int f_ = c1_ * 16 + (t >> 4);                                            \
        int bo_ = ((t & 15) * 16) ^ ((f_ & 7) << 4);                             \
        GLD16(w1t + (size_t)((Fb) + f_) * 128 + (bo_ >> 1),                      \
              db_ + c1_ * 4096 + wave * 1024);                                   \
    }                                                                            \
    _Pragma("unroll") for (int c2_ = 0; c2_ < 2; ++c2_) {                        \
        int op_ = c2_ * 32 + wave * 8 + ((t >> 3) & 7);                          \
        int pb_ = (t & 7) ^ ((t >> 3) & 7);                                      \
        int o_  = op_ * 2 + (pb_ >> 2);                                          \
        GLD16(w2t + (size_t)o_ * 2048 + (Fb) + (pb_ & 3) * 8,                    \
              db_ + 8192 + c2_ * 4096 + wave * 1024);                            \
    } }

#define FCOMP32(buf, Fb) {                                                       \
    const char* wb_ = (const char*)(buf);                                        \
    bf16x8 w2f_[8];                                                              \
    _Pragma("unroll") for (int c2_ = 0; c2_ < 8; ++c2_)                          \
        w2f_[c2_] = *(const bf16x8*)(wb_ + 8192 + (c2_ * 8 + (li >> 1)) * 128 +  \
            ((((li & 1) * 64) + g * 16) ^ ((li >> 1) << 4)));                    \
    _Pragma("unroll") for (int cf_ = 0; cf_ < 2; ++cf_) {                        \
        bf16x8 w1f_[4];                                                          \
        _Pragma("unroll") for (int ks_ = 0; ks_ < 4; ++ks_)                      \
            w1f_[ks_] = *(const bf16x8*)(wb_ + (cf_ * 16 + li) * 256 +           \
                ((ks_ * 64 + g * 16) ^ ((li & 7) << 4)));                        \
        f32x4 a0_ = (f32x4){0.f, 0.f, 0.f, 0.f};                                 \
        f32x4 a1_ = (f32x4){0.f, 0.f, 0.f, 0.f};                                 \
        _Pragma("unroll") for (int ks_ = 0; ks_ < 4; ++ks_) {                    \
            a0_ = __builtin_amdgcn_mfma_f32_16x16x32_bf16(af[0][ks_], w1f_[ks_], a0_, 0, 0, 0); \
            a1_ = __builtin_amdgcn_mfma_f32_16x16x32_bf16(af[1][ks_], w1f_[ks_], a1_, 0, 0, 0); \
        }                                                                        \
        float bias_ = b1[(Fb) + cf_ * 16 + li];                                  \
        u32 pkA0 = cvtpk(fmaxf(a0_[0] + bias_, 0.f), fmaxf(a0_[1] + bias_, 0.f)); \
        u32 pkA1 = cvtpk(fmaxf(a0_[2] + bias_, 0.f), fmaxf(a0_[3] + bias_, 0.f)); \
        u32 pkB0 = cvtpk(fmaxf(a1_[0] + bias_, 0.f), fmaxf(a1_[1] + bias_, 0.f)); \
        u32 pkB1 = cvtpk(fmaxf(a1_[2] + bias_, 0.f), fmaxf(a1_[3] + bias_, 0.f)); \
        int rp0_ = g * 2, rp1_ = g * 2 + 1;                                      \
        int wl_ = (cf_ * 16 + li) * 2;                                           \
        *(u16*)(hwb + rp0_ * 128 + ((wl_) ^ (rp0_ << 4)))        = (u16)pkA0;    \
        *(u16*)(hwb + rp0_ * 128 + ((64 + wl_) ^ (rp0_ << 4)))   = (u16)(pkA0 >> 16); \
        *(u16*)(hwb + rp1_ * 128 + ((wl_) ^ (rp1_ << 4)))        = (u16)pkA1;    \
        *(u16*)(hwb + rp1_ * 128 + ((64 + wl_) ^ (rp1_ << 4)))   = (u16)(pkA1 >> 16); \
        *(u16*)(hwb + (8 + rp0_) * 128 + ((wl_) ^ (rp0_ << 4)))      = (u16)pkB0; \
        *(u16*)(hwb + (8 + rp0_) * 128 + ((64 + wl_) ^ (rp0_ << 4))) = (u16)(pkB0 >> 16); \
        *(u16*)(hwb + (8 + rp1_) * 128 + ((wl_) ^ (rp1_ << 4)))      = (u16)pkB1; \
        *(u16*)(hwb + (8 + rp1_) * 128 + ((64 + wl_) ^ (rp1_ << 4))) = (u16)(pkB1 >> 16); \
    }                                                                            \
    {                                                                            \
        bf16x8 a2_[2];                                                           \
        _Pragma("unroll") for (int rf_ = 0; rf_ < 2; ++rf_)                      \
            a2_[rf_] = *(const bf16x8*)(hwb + (rf_ * 8 + (li >> 1)) * 128 +      \
                ((((li & 1) * 64) + g * 16) ^ ((li >> 1) << 4)));                \
        _Pragma("unroll") for (int c2_ = 0; c2_ < 8; ++c2_) {                    \
            acc2[0][c2_] = __builtin_amdgcn_mfma_f32_16x16x32_bf16(a2_[0], w2f_[c2_], acc2[0][c2_], 0, 0, 0); \
            acc2[1][c2_] = __builtin_amdgcn_mfma_f32_16x16x32_bf16(a2_[1], w2f_[c2_], acc2[1][c2_], 0, 0, 0); \
        }                                                                        \
    } }

__global__ __launch_bounds__(256, 3) void k_ffn(const u16* __restrict__ x1b,
        const u16* __restrict__ w1t, const u16* __restrict__ w2t,
        const float* __restrict__ b1, const float* __restrict__ b2,
        const float* __restrict__ g2, const float* __restrict__ bt2, float* __restrict__ out) {
    __shared__ u16 wA[8192];            // 16KB: W1 chunk (8KB) + W2 chunk (8KB)
    __shared__ u16 wB[8192];            // 16KB: buffer B
    __shared__ u16 hid[4][1024];        // per-wave [16 rp][128B] bf16 hidden (8KB total)
    int t = threadIdx.x, wave = t >> 6, lane = t & 63;
    int g = lane >> 4, li = lane & 15;
    size_t rowbase = (size_t)blockIdx.x * 128;
    char* hwb = (char*)&hid[wave][0];

    STAGE32(wA, 0);

    bf16x8 af[2][4];
    #pragma unroll
    for (int rf = 0; rf < 2; ++rf)
    #pragma unroll
    for (int ks = 0; ks < 4; ++ks)
        af[rf][ks] = *(const bf16x8*)(x1b +
            (rowbase + wave * 32 + rf * 16 + li) * 128 + ks * 32 + g * 8);

    f32x4 acc2[2][8];
    #pragma unroll
    for (int a = 0; a < 2; ++a)
    #pragma unroll
    for (int b = 0; b < 8; ++b) acc2[a][b] = (f32x4){0.f, 0.f, 0.f, 0.f};

    __syncthreads();                    // wA staged

    for (int F = 0; F < FFD; F += 64) {
        STAGE32(wB, F + 32);
        FCOMP32(wA, F);
        __syncthreads();
        if (F + 64 < FFD) STAGE32(wA, F + 64);
        FCOMP32(wB, F + 32);
        __syncthreads();
    }

    #pragma unroll
    for (int rf = 0; rf < 2; ++rf)
    #pragma unroll
    for (int r = 0; r < 4; ++r) {
        int lrow = wave * 32 + rf * 16 + g * 4 + r;
        size_t grow = rowbase + lrow;
        float vals[8], s1 = 0.f, s2 = 0.f;
        #pragma unroll
        for (int cf2 = 0; cf2 < 8; ++cf2) {
            int col = cf2 * 16 + li;
            float xv = bf2f(x1b[grow * 128 + col]);
            float y = xv + acc2[rf][cf2][r] + b2[col];
            vals[cf2] = y; s1 += y; s2 += y * y;
        }
        #pragma unroll
        for (int m = 1; m < 16; m <<= 1) {
            s1 += __shfl_xor(s1, m); s2 += __shfl_xor(s2, m);
        }
        float mu = s1 * (1.f / 128.f);
        float var = s2 * (1.f / 128.f) - mu * mu;
        float rs = rsqrtf(var + 1e-5f);
        #pragma unroll
        for (int cf2 = 0; cf2 < 8; ++cf2) {
            int col = cf2 * 16 + li;
            out[grow * 128 + col] = (vals[cf2] - mu) * rs * g2[col] + bt2[col];
        }
    }
}

// ---------------- launch ----------------
extern "C" void kernel_launch(void* const* d_in, const int* in_sizes, int n_in,
                              void* d_out, int out_size, void* d_ws, size_t ws_size,
                              hipStream_t stream) {
    const float* x   = (const float*)d_in[0];
    const int*   ei  = (const int*)d_in[1];
    const float *Wg1 = (const float*)d_in[2],  *bg1 = (const float*)d_in[3];
    const float *Wg2 = (const float*)d_in[4],  *bg2 = (const float*)d_in[5];
    const float *Wg3 = (const float*)d_in[6],  *bg3 = (const float*)d_in[7];
    const float *Wq  = (const float*)d_in[8],  *bq  = (const float*)d_in[9];
    const float *Wk  = (const float*)d_in[10], *bk  = (const float*)d_in[11];
    const float *Wv  = (const float*)d_in[12], *bv  = (const float*)d_in[13];
    const float *Wo  = (const float*)d_in[14], *bo  = (const float*)d_in[15];
    const float *g1  = (const float*)d_in[16], *b1n = (const float*)d_in[17];
    const float *W1  = (const float*)d_in[18], *b1  = (const float*)d_in[19];
    const float *W2  = (const float*)d_in[20], *b2  = (const float*)d_in[21];
    const float *g2  = (const float*)d_in[22], *bt2 = (const float*)d_in[23];

    char* ws = (char*)d_ws;
    int*   flag = (int*)(ws + 0);
    int*   cnt  = (int*)(ws + 4096);
    int*   rp   = (int*)(ws + 20480);
    int*   cur  = (int*)(ws + 40960);
    float* dinv = (float*)(ws + 57344);
    float* msA  = (float*)(ws + 73728);      // 2 MB (L1 ms, later ms32)
    int*   es   = (int*)(ws + 2170880);      // 512 KB
    float* msB  = (float*)(ws + 2695168);    // 2 MB (L2 ms)
    float* tc   = (float*)(ws + 6889472);
    u16*   w1t  = (u16*)(ws + 6897664);      // 512 KB
    u16*   w2t  = (u16*)(ws + 7421952);      // 512 KB
    u16*   x1b  = (u16*)(ws + 8388608);      // 32 MB bf16 x1
    float* ms32 = msA;                       // reuse L1 buffer for 32-wide ms
    float* out  = (float*)d_out;

    k_init<<<17, 256, 0, stream>>>(ei, flag, cnt);
    k_degi<<<512, 256, 0, stream>>>(ei, flag, cnt);
    k_scan<<<1, 1024, 0, stream>>>(cnt, rp, cur, dinv);

    // fused: bucket + GCN mm1 + tiled weight transpose + prep  (mm1 -> msA)
    k_fuse1<<<2689, 256, 0, stream>>>(ei, flag, cur, es, x, Wg1, dinv, msA,
                                      W1, W2, w1t, w2t,
                                      Wq, bq, Wk, bk, Wv, bv, Wo, bo, tc);

    // gather L1 + mm Wg2 -> msB ; gather L2 + mm Wg3 -> ms32
    k_gm2<<<1024, 256, 0, stream>>>(es, rp, msA, dinv, bg1, Wg2, msB);
    k_gm3<<<1024, 256, 0, stream>>>(es, rp, msB, dinv, bg2, Wg3, ms32);

    // fused gather(32) + attention + LN1 -> x1 (bf16)
    k_ga<<<2048, 256, 0, stream>>>(es, rp, ms32, dinv, bg3, tc, g1, b1n, x1b);

    // FFN + residual + LN2 -> out (fp32, d_out)
    k_ffn<<<1024, 256, 0, stream>>>(x1b, w1t, w2t, b1, b2, g2, bt2, out);
}